// Round 3
// baseline (711.175 us; speedup 1.0000x reference)
//
#include <hip/hip_runtime.h>
#include <math.h>

#define DD 8
#define HH 4
#define EE 4
#define NLAYER 4
#define BB 4
#define SS 20
#define IMM 64

static constexpr int NPOS = BB * SS * IMM * IMM;          // 327680
static constexpr size_t ZBYTES = (size_t)NPOS * DD * 4;   // 10485760

// ---------------------------------------------------------------------------
__global__ __launch_bounds__(256)
void emb_kernel(const float* __restrict__ x, const float* __restrict__ conv_w,
                const float* __restrict__ pos_s, const float* __restrict__ pos_h,
                const float* __restrict__ pos_w, float* __restrict__ xt) {
    int idx = blockIdx.x * 256 + threadIdx.x;
    if (idx >= NPOS) return;
    int j = idx & 63;
    int i = (idx >> 6) & 63;
    int s = (idx >> 12) % SS;
    float xv = x[idx];
    float o[8];
#pragma unroll
    for (int d = 0; d < 8; ++d) {
        float v = xv * conv_w[d];
        v = v > 0.f ? v : 0.f;
        o[d] = v + pos_s[s * 8 + d] + pos_h[d * 64 + i] + pos_w[d * 64 + j];
    }
    float4* dst = (float4*)(xt + (size_t)idx * 8);
    dst[0] = make_float4(o[0], o[1], o[2], o[3]);
    dst[1] = make_float4(o[4], o[5], o[6], o[7]);
}

__device__ __forceinline__ float dot4(float4 a, float4 b) {
    return a.x * b.x + a.y * b.y + a.z * b.z + a.w * b.w;
}

// ---------------------------------------------------------------------------
// Axis attention: LINES lines per block, one thread per (line, head, row).
// Pass 1 computes only the row max (no dots[] array -> low VGPR); pass 2
// recomputes dp and fuses exp+sum+PV. All reductions split 4-way for ILP.
template <int L, int LINES, bool ACCUM>
__global__ __launch_bounds__(LINES * HH * L)
void attn_kernel(const float* __restrict__ src, float* __restrict__ dst,
                 const float* __restrict__ Wq, const float* __restrict__ Wkv,
                 const float* __restrict__ Wo, const float* __restrict__ bo,
                 int m0, int c1, int m1, int stride) {
    constexpr int NT = LINES * HH * L;
    constexpr int LL = LINES * L;
    __shared__ float4 zl4[2][LL];      // z line, quad-major (conflict-free)
    __shared__ float4 kv4[LL][8];      // quads 0..3 = K heads, 4..7 = V heads
    __shared__ float4 olT4[HH][LL];    // attention out, head-major
    __shared__ float4 wq4[8][4];       // wq4[d][h]
    __shared__ float4 wkv4[8][8];      // wkv4[d][c]
    __shared__ float  wo_sT[8][16];    // wo_sT[d][c] = Wo[c][d]
    __shared__ float  bo_s[8];

    const int t = threadIdx.x;
    if (t < 32)  wq4[t >> 2][t & 3] = *(const float4*)(Wq + t * 4);
    if (t < 64)  wkv4[t >> 3][t & 7] = *(const float4*)(Wkv + t * 4);
    if (t < 128) wo_sT[t >> 4][t & 15] = Wo[(t & 15) * 8 + (t >> 4)];
    if (t < 8)   bo_s[t] = bo[t];

    size_t base[LINES];
#pragma unroll
    for (int ln = 0; ln < LINES; ++ln) {
        int lid = blockIdx.x * LINES + ln;
        int u0 = lid & 63;
        int rest = lid >> 6;
        int u1 = rest % c1;
        int b  = rest / c1;
        base[ln] = (size_t)b * 655360 + (size_t)u1 * m1 + (size_t)u0 * m0;
    }

    // stage z line(s)
    for (int idx = t; idx < LL * 2; idx += NT) {
        int q = idx & 1, lp = idx >> 1;
        int ln = lp / L, p = lp % L;
        zl4[q][lp] = *(const float4*)(src + base[ln] + (size_t)p * stride + q * 4);
    }
    __syncthreads();

    // K,V projection
    for (int idx = t; idx < LL * 8; idx += NT) {
        int c = idx & 7, lp = idx >> 3;
        float4 z0 = zl4[0][lp], z1 = zl4[1][lp];
        const float zs[8] = {z0.x, z0.y, z0.z, z0.w, z1.x, z1.y, z1.z, z1.w};
        float4 acc = make_float4(0.f, 0.f, 0.f, 0.f);
#pragma unroll
        for (int d = 0; d < 8; ++d) {
            float4 w = wkv4[d][c];
            acc.x += zs[d] * w.x; acc.y += zs[d] * w.y;
            acc.z += zs[d] * w.z; acc.w += zs[d] * w.w;
        }
        kv4[lp][c] = acc;
    }
    __syncthreads();

    // Attention: thread = (line, head, row)
    {
        const int ln = t / (HH * L);
        const int r  = t % (HH * L);
        const int h  = r / L;
        const int i  = r % L;
        const int jb = ln * L;
        float4 z0 = zl4[0][jb + i], z1 = zl4[1][jb + i];
        const float zs[8] = {z0.x, z0.y, z0.z, z0.w, z1.x, z1.y, z1.z, z1.w};
        float4 q = make_float4(0.f, 0.f, 0.f, 0.f);
#pragma unroll
        for (int d = 0; d < 8; ++d) {
            float4 w = wq4[d][h];
            q.x += zs[d] * w.x; q.y += zs[d] * w.y;
            q.z += zs[d] * w.z; q.w += zs[d] * w.w;
        }
        q.x *= 0.5f; q.y *= 0.5f; q.z *= 0.5f; q.w *= 0.5f;   // E^-0.5

        // pass 1: row max, 4-way split chains, no dots storage
        float mx0 = -1e30f, mx1 = -1e30f, mx2 = -1e30f, mx3 = -1e30f;
#pragma unroll
        for (int j = 0; j < L; j += 4) {
            mx0 = fmaxf(mx0, dot4(q, kv4[jb + j + 0][h]));
            mx1 = fmaxf(mx1, dot4(q, kv4[jb + j + 1][h]));
            mx2 = fmaxf(mx2, dot4(q, kv4[jb + j + 2][h]));
            mx3 = fmaxf(mx3, dot4(q, kv4[jb + j + 3][h]));
        }
        const float m = fmaxf(fmaxf(mx0, mx1), fmaxf(mx2, mx3));

        // pass 2: recompute dp, fused exp + sum + PV, 4-way accumulators
        float s0 = 0.f, s1 = 0.f, s2 = 0.f, s3 = 0.f;
        float4 oa = make_float4(0.f, 0.f, 0.f, 0.f);
        float4 ob = oa, oc = oa, od = oa;
#pragma unroll
        for (int j = 0; j < L; j += 4) {
            float p0 = __expf(dot4(q, kv4[jb + j + 0][h]) - m);
            float p1 = __expf(dot4(q, kv4[jb + j + 1][h]) - m);
            float p2 = __expf(dot4(q, kv4[jb + j + 2][h]) - m);
            float p3 = __expf(dot4(q, kv4[jb + j + 3][h]) - m);
            s0 += p0; s1 += p1; s2 += p2; s3 += p3;
            float4 v0 = kv4[jb + j + 0][4 + h];
            float4 v1 = kv4[jb + j + 1][4 + h];
            float4 v2 = kv4[jb + j + 2][4 + h];
            float4 v3 = kv4[jb + j + 3][4 + h];
            oa.x += p0 * v0.x; oa.y += p0 * v0.y; oa.z += p0 * v0.z; oa.w += p0 * v0.w;
            ob.x += p1 * v1.x; ob.y += p1 * v1.y; ob.z += p1 * v1.z; ob.w += p1 * v1.w;
            oc.x += p2 * v2.x; oc.y += p2 * v2.y; oc.z += p2 * v2.z; oc.w += p2 * v2.w;
            od.x += p3 * v3.x; od.y += p3 * v3.y; od.z += p3 * v3.z; od.w += p3 * v3.w;
        }
        const float inv = 1.f / (s0 + s1 + s2 + s3);
        float4 oe;
        oe.x = (oa.x + ob.x + oc.x + od.x) * inv;
        oe.y = (oa.y + ob.y + oc.y + od.y) * inv;
        oe.z = (oa.z + ob.z + oc.z + od.z) * inv;
        oe.w = (oa.w + ob.w + oc.w + od.w) * inv;
        olT4[h][jb + i] = oe;
    }
    __syncthreads();

    // Output projection (+ optional accumulate). NT % 8 == 0 -> d fixed per thread.
    {
        const int d = t & 7;
        float4 w0 = *(const float4*)&wo_sT[d][0];
        float4 w1 = *(const float4*)&wo_sT[d][4];
        float4 w2 = *(const float4*)&wo_sT[d][8];
        float4 w3 = *(const float4*)&wo_sT[d][12];
        float bod = bo_s[d];
        for (int idx = t; idx < LL * 8; idx += NT) {
            int lp = idx >> 3;
            int ln = lp / L, p = lp % L;
            float4 o0 = olT4[0][lp], o1 = olT4[1][lp];
            float4 o2 = olT4[2][lp], o3 = olT4[3][lp];
            float acc = bod
                + o0.x * w0.x + o0.y * w0.y + o0.z * w0.z + o0.w * w0.w
                + o1.x * w1.x + o1.y * w1.y + o1.z * w1.z + o1.w * w1.w
                + o2.x * w2.x + o2.y * w2.y + o2.z * w2.z + o2.w * w2.w
                + o3.x * w3.x + o3.y * w3.y + o3.z * w3.z + o3.w * w3.w;
            size_t gi = base[ln] + (size_t)p * stride + d;
            if (ACCUM) dst[gi] += acc;
            else       dst[gi] = acc;
        }
    }
}

// ---------------------------------------------------------------------------
__global__ __launch_bounds__(256)
void reduce_kernel(const float* __restrict__ z, const float* __restrict__ xt,
                   const float* __restrict__ Wc, float* __restrict__ accum) {
    const int b  = blockIdx.x >> 4;
    const int ij = ((blockIdx.x & 15) << 8) + threadIdx.x;
    float4 m0 = make_float4(-1e30f, -1e30f, -1e30f, -1e30f);
    float4 m1 = m0;
    for (int s = 0; s < SS; ++s) {
        size_t off = (((size_t)(b * SS + s)) * 4096 + ij) * 8;
        float4 a0 = *(const float4*)(z + off);
        float4 a1 = *(const float4*)(z + off + 4);
        float4 c0 = *(const float4*)(xt + off);
        float4 c1 = *(const float4*)(xt + off + 4);
        m0.x = fmaxf(m0.x, a0.x + c0.x); m0.y = fmaxf(m0.y, a0.y + c0.y);
        m0.z = fmaxf(m0.z, a0.z + c0.z); m0.w = fmaxf(m0.w, a0.w + c0.w);
        m1.x = fmaxf(m1.x, a1.x + c1.x); m1.y = fmaxf(m1.y, a1.y + c1.y);
        m1.z = fmaxf(m1.z, a1.z + c1.z); m1.w = fmaxf(m1.w, a1.w + c1.w);
    }
    float partial =
        m0.x * Wc[0 * 4096 + ij] + m0.y * Wc[1 * 4096 + ij] +
        m0.z * Wc[2 * 4096 + ij] + m0.w * Wc[3 * 4096 + ij] +
        m1.x * Wc[4 * 4096 + ij] + m1.y * Wc[5 * 4096 + ij] +
        m1.z * Wc[6 * 4096 + ij] + m1.w * Wc[7 * 4096 + ij];

    __shared__ float red[256];
    red[threadIdx.x] = partial;
    __syncthreads();
#pragma unroll
    for (int off = 128; off > 0; off >>= 1) {
        if (threadIdx.x < off) red[threadIdx.x] += red[threadIdx.x + off];
        __syncthreads();
    }
    if (threadIdx.x == 0) atomicAdd(&accum[b], red[0]);
}

__global__ void final_kernel(const float* __restrict__ accum,
                             const float* __restrict__ bc,
                             float* __restrict__ out) {
    int b = threadIdx.x;
    if (b < BB) out[b] = 1.f / (1.f + expf(-(accum[b] + bc[0])));
}

// ---------------------------------------------------------------------------
extern "C" void kernel_launch(void* const* d_in, const int* in_sizes, int n_in,
                              void* d_out, int out_size, void* d_ws, size_t ws_size,
                              hipStream_t stream) {
    const float* x      = (const float*)d_in[0];
    const float* conv_w = (const float*)d_in[1];
    const float* pos_s  = (const float*)d_in[2];
    const float* pos_h  = (const float*)d_in[3];
    const float* pos_w  = (const float*)d_in[4];
    const float* Wq     = (const float*)d_in[5];
    const float* Wkv    = (const float*)d_in[6];
    const float* Wo     = (const float*)d_in[7];
    const float* bo     = (const float*)d_in[8];
    const float* Wc     = (const float*)d_in[9];
    const float* bc     = (const float*)d_in[10];
    float* out = (float*)d_out;

    char* ws = (char*)d_ws;
    float* xt    = (float*)(ws);
    float* zA    = (float*)(ws + ZBYTES);
    float* zB    = (float*)(ws + 2 * ZBYTES);
    float* accum = (float*)(ws + 3 * ZBYTES);

    emb_kernel<<<NPOS / 256, 256, 0, stream>>>(x, conv_w, pos_s, pos_h, pos_w, xt);

    const float* cur = xt;
    float* bufs[2] = {zA, zB};
    int w = 0;
    for (int l = 0; l < NLAYER; ++l) {
        float* dstp = bufs[w];
        const float* wq0  = Wq  + (size_t)(l * 3 + 0) * 128;
        const float* wkv0 = Wkv + (size_t)(l * 3 + 0) * 256;
        const float* wo0  = Wo  + (size_t)(l * 3 + 0) * 128;
        const float* bo0  = bo  + (size_t)(l * 3 + 0) * 8;
        // a=0: attend over s (L=20), 4 lines/block
        attn_kernel<SS, 4, false><<<BB * IMM * IMM / 4, SS * 4 * HH, 0, stream>>>(
            cur, dstp, wq0, wkv0, wo0, bo0, 8, 64, 512, 32768);
        // a=1: attend over i (L=64)
        attn_kernel<IMM, 1, true><<<BB * SS * IMM, IMM * HH, 0, stream>>>(
            cur, dstp, wq0 + 128, wkv0 + 256, wo0 + 128, bo0 + 8, 8, 20, 32768, 512);
        // a=2: attend over j (L=64)
        attn_kernel<IMM, 1, true><<<BB * SS * IMM, IMM * HH, 0, stream>>>(
            cur, dstp, wq0 + 256, wkv0 + 512, wo0 + 256, bo0 + 16, 512, 20, 32768, 8);
        cur = dstp;
        w ^= 1;
    }

    hipMemsetAsync(accum, 0, BB * sizeof(float), stream);
    reduce_kernel<<<BB * 16, 256, 0, stream>>>(cur, xt, Wc, accum);
    final_kernel<<<1, 64, 0, stream>>>(accum, bc, out);
}

// Round 4
// 675.384 us; speedup vs baseline: 1.0530x; 1.0530x over previous
//
#include <hip/hip_runtime.h>
#include <math.h>

#define DD 8
#define HH 4
#define EE 4
#define NLAYER 4
#define BB 4
#define SS 20
#define IMM 64

static constexpr int NPOS = BB * SS * IMM * IMM;          // 327680
static constexpr size_t ZBYTES = (size_t)NPOS * DD * 4;   // 10485760

// ---------------------------------------------------------------------------
__global__ __launch_bounds__(256)
void emb_kernel(const float* __restrict__ x, const float* __restrict__ conv_w,
                const float* __restrict__ pos_s, const float* __restrict__ pos_h,
                const float* __restrict__ pos_w, float* __restrict__ xt) {
    int idx = blockIdx.x * 256 + threadIdx.x;
    if (idx >= NPOS) return;
    int j = idx & 63;
    int i = (idx >> 6) & 63;
    int s = (idx >> 12) % SS;
    float xv = x[idx];
    float o[8];
#pragma unroll
    for (int d = 0; d < 8; ++d) {
        float v = xv * conv_w[d];
        v = v > 0.f ? v : 0.f;
        o[d] = v + pos_s[s * 8 + d] + pos_h[d * 64 + i] + pos_w[d * 64 + j];
    }
    float4* dst = (float4*)(xt + (size_t)idx * 8);
    dst[0] = make_float4(o[0], o[1], o[2], o[3]);
    dst[1] = make_float4(o[4], o[5], o[6], o[7]);
}

__device__ __forceinline__ float dot4(float4 a, float4 b) {
    return a.x * b.x + a.y * b.y + a.z * b.z + a.w * b.w;
}

// ---------------------------------------------------------------------------
// Axis attention. RPT query rows per thread: each kv LDS read is amortized
// over RPT dot products (the kernel is LDS-issue-bound, m134: b128 ~12cyc).
// Two-pass softmax with QK recompute (keeps VGPR low). STG selects staging/
// output iteration order: 1 = line-fastest (coalesces adjacent-line bases),
// 0 = position-fastest (coalesces contiguous lines, a=2).
template <int L, int RPT, int LINES, bool ACCUM, int STG>
__global__ __launch_bounds__(HH * (L / RPT) * LINES)
void attn_kernel(const float* __restrict__ src, float* __restrict__ dst,
                 const float* __restrict__ Wq, const float* __restrict__ Wkv,
                 const float* __restrict__ Wo, const float* __restrict__ bo,
                 int m0, int c1, int m1, int stride) {
    constexpr int RG = L / RPT;          // row-groups per (line, head)
    constexpr int TL = HH * RG;          // threads per line
    constexpr int NT = TL * LINES;       // block size
    constexpr int LL = L * LINES;

    __shared__ float4 zl4[2][LL];        // z line, 2 quads per position
    __shared__ float4 kv4[LL][8];        // quads 0..3 = K heads, 4..7 = V heads
    __shared__ float4 olT4[HH][LL];      // attention out, head-major
    __shared__ float4 wq4[8][4];         // wq4[d][h]
    __shared__ float4 wkv4[8][8];        // wkv4[d][c]
    __shared__ float4 woq4[16][2];       // woq4[c][dq] = Wo[c][4dq..4dq+3]
    __shared__ float4 bo4_s[2];

    const int t = threadIdx.x;
    if (t < 32) wq4[t >> 2][t & 3]  = *(const float4*)(Wq  + t * 4);
    if (t < 64) wkv4[t >> 3][t & 7] = *(const float4*)(Wkv + t * 4);
    if (t < 32) woq4[t >> 1][t & 1] = *(const float4*)(Wo  + t * 4);
    if (t < 2)  bo4_s[t]            = *(const float4*)(bo  + t * 4);

    // line base address from line id (recomputed per use; no dynamic array)
    auto line_base = [&](int ln) -> size_t {
        int lid = blockIdx.x * LINES + ln;
        int u0 = lid & 63;
        int rest = lid >> 6;
        int u1 = rest % c1;
        int b  = rest / c1;
        return (size_t)b * 655360 + (size_t)u1 * m1 + (size_t)u0 * m0;
    };

    // ---- stage z ----
    for (int idx = t; idx < LL * 2; idx += NT) {
        int q, ln, p;
        if (STG == 1) { q = idx & 1; int r = idx >> 1; ln = r % LINES; p = r / LINES; }
        else          { q = idx & 1; int r = idx >> 1; ln = r / L;     p = r % L;     }
        zl4[q][ln * L + p] = *(const float4*)(src + line_base(ln) + (size_t)p * stride + q * 4);
    }
    __syncthreads();

    // ---- K,V projection (w-column preloaded; c fixed per thread) ----
    {
        const int c = t & 7;
        float4 wc[8];
#pragma unroll
        for (int d = 0; d < 8; ++d) wc[d] = wkv4[d][c];
        for (int idx = t; idx < LL * 8; idx += NT) {
            int lp = idx >> 3;
            float4 z0 = zl4[0][lp], z1 = zl4[1][lp];
            const float zs[8] = {z0.x, z0.y, z0.z, z0.w, z1.x, z1.y, z1.z, z1.w};
            float4 acc = make_float4(0.f, 0.f, 0.f, 0.f);
#pragma unroll
            for (int d = 0; d < 8; ++d) {
                acc.x += zs[d] * wc[d].x; acc.y += zs[d] * wc[d].y;
                acc.z += zs[d] * wc[d].z; acc.w += zs[d] * wc[d].w;
            }
            kv4[lp][c] = acc;
        }
    }
    __syncthreads();

    // ---- attention: thread = (line, head, row-group of RPT rows) ----
    {
        const int ln = t / TL;
        const int r  = t % TL;
        const int h  = r / RG;
        const int rg = r % RG;
        const int jb = ln * L;
        const int i0 = rg * RPT;

        float4 q[RPT];
#pragma unroll
        for (int k = 0; k < RPT; ++k) {
            float4 z0 = zl4[0][jb + i0 + k], z1 = zl4[1][jb + i0 + k];
            const float zs[8] = {z0.x, z0.y, z0.z, z0.w, z1.x, z1.y, z1.z, z1.w};
            float4 acc = make_float4(0.f, 0.f, 0.f, 0.f);
#pragma unroll
            for (int d = 0; d < 8; ++d) {
                float4 w = wq4[d][h];
                acc.x += zs[d] * w.x; acc.y += zs[d] * w.y;
                acc.z += zs[d] * w.z; acc.w += zs[d] * w.w;
            }
            q[k] = make_float4(acc.x * 0.5f, acc.y * 0.5f, acc.z * 0.5f, acc.w * 0.5f);
        }

        // pass 1: row maxes (one kv read serves RPT rows)
        float mx[RPT];
#pragma unroll
        for (int k = 0; k < RPT; ++k) mx[k] = -1e30f;
#pragma unroll 8
        for (int j = 0; j < L; ++j) {
            float4 kk = kv4[jb + j][h];
#pragma unroll
            for (int k = 0; k < RPT; ++k) mx[k] = fmaxf(mx[k], dot4(q[k], kk));
        }

        // pass 2: recompute dp, fused exp + sum + PV
        float s[RPT];
        float4 o[RPT];
#pragma unroll
        for (int k = 0; k < RPT; ++k) { s[k] = 0.f; o[k] = make_float4(0.f, 0.f, 0.f, 0.f); }
#pragma unroll 8
        for (int j = 0; j < L; ++j) {
            float4 kk = kv4[jb + j][h];
            float4 vv = kv4[jb + j][4 + h];
#pragma unroll
            for (int k = 0; k < RPT; ++k) {
                float p = __expf(dot4(q[k], kk) - mx[k]);
                s[k] += p;
                o[k].x += p * vv.x; o[k].y += p * vv.y;
                o[k].z += p * vv.z; o[k].w += p * vv.w;
            }
        }
#pragma unroll
        for (int k = 0; k < RPT; ++k) {
            float inv = 1.f / s[k];
            olT4[h][jb + i0 + k] =
                make_float4(o[k].x * inv, o[k].y * inv, o[k].z * inv, o[k].w * inv);
        }
    }
    __syncthreads();

    // ---- output projection, float4 per (position, d-quad) ----
    {
        const int dq = t & 1;
        float4 wr[16];
#pragma unroll
        for (int c = 0; c < 16; ++c) wr[c] = woq4[c][dq];
        float4 bo4 = bo4_s[dq];
        for (int idx = t; idx < LL * 2; idx += NT) {
            int ln, p;
            if (STG == 1) { int r = idx >> 1; ln = r % LINES; p = r / LINES; }
            else          { int r = idx >> 1; ln = r / L;     p = r % L;     }
            int lp = ln * L + p;
            float4 o0 = olT4[0][lp], o1 = olT4[1][lp];
            float4 o2 = olT4[2][lp], o3 = olT4[3][lp];
            const float oc[16] = {o0.x, o0.y, o0.z, o0.w, o1.x, o1.y, o1.z, o1.w,
                                  o2.x, o2.y, o2.z, o2.w, o3.x, o3.y, o3.z, o3.w};
            float4 acc = bo4;
#pragma unroll
            for (int c = 0; c < 16; ++c) {
                acc.x += oc[c] * wr[c].x; acc.y += oc[c] * wr[c].y;
                acc.z += oc[c] * wr[c].z; acc.w += oc[c] * wr[c].w;
            }
            float* gp = dst + line_base(ln) + (size_t)p * stride + dq * 4;
            if (ACCUM) {
                float4 old = *(const float4*)gp;
                acc.x += old.x; acc.y += old.y; acc.z += old.z; acc.w += old.w;
            }
            *(float4*)gp = acc;
        }
    }
}

// ---------------------------------------------------------------------------
__global__ __launch_bounds__(256)
void reduce_kernel(const float* __restrict__ z, const float* __restrict__ xt,
                   const float* __restrict__ Wc, float* __restrict__ accum) {
    const int b  = blockIdx.x >> 4;
    const int ij = ((blockIdx.x & 15) << 8) + threadIdx.x;
    float4 m0 = make_float4(-1e30f, -1e30f, -1e30f, -1e30f);
    float4 m1 = m0;
    for (int s = 0; s < SS; ++s) {
        size_t off = (((size_t)(b * SS + s)) * 4096 + ij) * 8;
        float4 a0 = *(const float4*)(z + off);
        float4 a1 = *(const float4*)(z + off + 4);
        float4 c0 = *(const float4*)(xt + off);
        float4 c1 = *(const float4*)(xt + off + 4);
        m0.x = fmaxf(m0.x, a0.x + c0.x); m0.y = fmaxf(m0.y, a0.y + c0.y);
        m0.z = fmaxf(m0.z, a0.z + c0.z); m0.w = fmaxf(m0.w, a0.w + c0.w);
        m1.x = fmaxf(m1.x, a1.x + c1.x); m1.y = fmaxf(m1.y, a1.y + c1.y);
        m1.z = fmaxf(m1.z, a1.z + c1.z); m1.w = fmaxf(m1.w, a1.w + c1.w);
    }
    float partial =
        m0.x * Wc[0 * 4096 + ij] + m0.y * Wc[1 * 4096 + ij] +
        m0.z * Wc[2 * 4096 + ij] + m0.w * Wc[3 * 4096 + ij] +
        m1.x * Wc[4 * 4096 + ij] + m1.y * Wc[5 * 4096 + ij] +
        m1.z * Wc[6 * 4096 + ij] + m1.w * Wc[7 * 4096 + ij];

    __shared__ float red[256];
    red[threadIdx.x] = partial;
    __syncthreads();
#pragma unroll
    for (int off = 128; off > 0; off >>= 1) {
        if (threadIdx.x < off) red[threadIdx.x] += red[threadIdx.x + off];
        __syncthreads();
    }
    if (threadIdx.x == 0) atomicAdd(&accum[b], red[0]);
}

__global__ void final_kernel(const float* __restrict__ accum,
                             const float* __restrict__ bc,
                             float* __restrict__ out) {
    int b = threadIdx.x;
    if (b < BB) out[b] = 1.f / (1.f + expf(-(accum[b] + bc[0])));
}

// ---------------------------------------------------------------------------
extern "C" void kernel_launch(void* const* d_in, const int* in_sizes, int n_in,
                              void* d_out, int out_size, void* d_ws, size_t ws_size,
                              hipStream_t stream) {
    const float* x      = (const float*)d_in[0];
    const float* conv_w = (const float*)d_in[1];
    const float* pos_s  = (const float*)d_in[2];
    const float* pos_h  = (const float*)d_in[3];
    const float* pos_w  = (const float*)d_in[4];
    const float* Wq     = (const float*)d_in[5];
    const float* Wkv    = (const float*)d_in[6];
    const float* Wo     = (const float*)d_in[7];
    const float* bo     = (const float*)d_in[8];
    const float* Wc     = (const float*)d_in[9];
    const float* bc     = (const float*)d_in[10];
    float* out = (float*)d_out;

    char* ws = (char*)d_ws;
    float* xt    = (float*)(ws);
    float* zA    = (float*)(ws + ZBYTES);
    float* zB    = (float*)(ws + 2 * ZBYTES);
    float* accum = (float*)(ws + 3 * ZBYTES);

    emb_kernel<<<NPOS / 256, 256, 0, stream>>>(x, conv_w, pos_s, pos_h, pos_w, xt);

    const float* cur = xt;
    float* bufs[2] = {zA, zB};
    int w = 0;
    for (int l = 0; l < NLAYER; ++l) {
        float* dstp = bufs[w];
        const float* wq0  = Wq  + (size_t)(l * 3 + 0) * 128;
        const float* wkv0 = Wkv + (size_t)(l * 3 + 0) * 256;
        const float* wo0  = Wo  + (size_t)(l * 3 + 0) * 128;
        const float* bo0  = bo  + (size_t)(l * 3 + 0) * 8;
        // a=0: attend over s (L=20). RPT=5, 8 lines/block (16 thr/line), 128 thr.
        attn_kernel<SS, 5, 8, false, 1><<<BB * IMM * IMM / 8, 128, 0, stream>>>(
            cur, dstp, wq0, wkv0, wo0, bo0, 8, 64, 512, 32768);
        // a=1: attend over i (L=64). RPT=4, 2 lines/block (64 thr/line), 128 thr.
        attn_kernel<IMM, 4, 2, true, 1><<<BB * SS * IMM / 2, 128, 0, stream>>>(
            cur, dstp, wq0 + 128, wkv0 + 256, wo0 + 128, bo0 + 8, 8, 20, 32768, 512);
        // a=2: attend over j (L=64), contiguous lines -> position-fastest staging.
        attn_kernel<IMM, 4, 2, true, 0><<<BB * SS * IMM / 2, 128, 0, stream>>>(
            cur, dstp, wq0 + 256, wkv0 + 512, wo0 + 256, bo0 + 16, 512, 20, 32768, 8);
        cur = dstp;
        w ^= 1;
    }

    hipMemsetAsync(accum, 0, BB * sizeof(float), stream);
    reduce_kernel<<<BB * 16, 256, 0, stream>>>(cur, xt, Wc, accum);
    final_kernel<<<1, 64, 0, stream>>>(accum, bc, out);
}

// Round 7
// 530.606 us; speedup vs baseline: 1.3403x; 1.2729x over previous
//
#include <hip/hip_runtime.h>
#include <math.h>

#define DD 8
#define HH 4
#define EE 4
#define NLAYER 4
#define BB 4
#define SS 20
#define IMM 64

static constexpr int NPOS = BB * SS * IMM * IMM;          // 327680
static constexpr size_t ZBYTES = (size_t)NPOS * DD * 4;   // 10485760

// ---------------------------------------------------------------------------
__global__ __launch_bounds__(256)
void emb_kernel(const float* __restrict__ x, const float* __restrict__ conv_w,
                const float* __restrict__ pos_s, const float* __restrict__ pos_h,
                const float* __restrict__ pos_w, float* __restrict__ xt) {
    int idx = blockIdx.x * 256 + threadIdx.x;
    if (idx >= NPOS) return;
    int j = idx & 63;
    int i = (idx >> 6) & 63;
    int s = (idx >> 12) % SS;
    float xv = x[idx];
    float o[8];
#pragma unroll
    for (int d = 0; d < 8; ++d) {
        float v = xv * conv_w[d];
        v = v > 0.f ? v : 0.f;
        o[d] = v + pos_s[s * 8 + d] + pos_h[d * 64 + i] + pos_w[d * 64 + j];
    }
    float4* dst = (float4*)(xt + (size_t)idx * 8);
    dst[0] = make_float4(o[0], o[1], o[2], o[3]);
    dst[1] = make_float4(o[4], o[5], o[6], o[7]);
}

__device__ __forceinline__ float dot4(float4 a, float4 b) {
    return fmaf(a.w, b.w, fmaf(a.z, b.z, fmaf(a.y, b.y, a.x * b.x)));
}

// ---------------------------------------------------------------------------
// Axis attention. One query row per thread (max TLP: 80 waves/CU for L=64).
// Chunked online softmax (CH dots in registers per chunk, flash-style merge)
// keeps VGPR <= 64 (enforced by __launch_bounds__(.,8)) -> 32-wave/CU cap.
// STG: staging/output iteration order (1 = line-fastest, 0 = position-fastest).
template <int L, int CH, int LINES, bool ACCUM, int STG>
__global__ __launch_bounds__(HH * L * LINES, 8)
void attn_kernel(const float* __restrict__ src, float* __restrict__ dst,
                 const float* __restrict__ Wq, const float* __restrict__ Wkv,
                 const float* __restrict__ Wo, const float* __restrict__ bo,
                 int m0, int c1, int m1, int stride) {
    constexpr int TL = HH * L;           // threads per line
    constexpr int NT = TL * LINES;       // block size
    constexpr int LL = L * LINES;

    __shared__ float4 zl4[2][LL];        // z line, 2 quads per position
    __shared__ float4 kv4[LL][8];        // quads 0..3 = K heads, 4..7 = V heads
    __shared__ float4 olT4[HH][LL];      // attention out, head-major
    __shared__ float4 wq4[8][4];         // wq4[d][h]
    __shared__ float4 wkv4[8][8];        // wkv4[d][c]
    __shared__ float4 woq4[16][2];       // woq4[c][dq] = Wo[c][4dq..4dq+3]
    __shared__ float4 bo4_s[2];

    const int t = threadIdx.x;
    if (t < 32) wq4[t >> 2][t & 3]  = *(const float4*)(Wq  + t * 4);
    if (t < 64) wkv4[t >> 3][t & 7] = *(const float4*)(Wkv + t * 4);
    if (t < 32) woq4[t >> 1][t & 1] = *(const float4*)(Wo  + t * 4);
    if (t < 2)  bo4_s[t]            = *(const float4*)(bo  + t * 4);

    auto line_base = [&](int ln) -> size_t {
        int lid = blockIdx.x * LINES + ln;
        int u0 = lid & 63;
        int rest = lid >> 6;
        int u1 = rest % c1;
        int b  = rest / c1;
        return (size_t)b * 655360 + (size_t)u1 * m1 + (size_t)u0 * m0;
    };

    // ---- stage z ----
    for (int idx = t; idx < LL * 2; idx += NT) {
        int q, ln, p;
        if (STG == 1) { q = idx & 1; int r = idx >> 1; ln = r % LINES; p = r / LINES; }
        else          { q = idx & 1; int r = idx >> 1; ln = r / L;     p = r % L;     }
        zl4[q][ln * L + p] = *(const float4*)(src + line_base(ln) + (size_t)p * stride + q * 4);
    }
    __syncthreads();

    // ---- K,V projection (w-column preloaded; c fixed per thread) ----
    {
        const int c = t & 7;
        float4 wc[8];
#pragma unroll
        for (int d = 0; d < 8; ++d) wc[d] = wkv4[d][c];
        for (int idx = t; idx < LL * 8; idx += NT) {
            int lp = idx >> 3;
            float4 z0 = zl4[0][lp], z1 = zl4[1][lp];
            const float zs[8] = {z0.x, z0.y, z0.z, z0.w, z1.x, z1.y, z1.z, z1.w};
            float4 acc = make_float4(0.f, 0.f, 0.f, 0.f);
#pragma unroll
            for (int d = 0; d < 8; ++d) {
                acc.x += zs[d] * wc[d].x; acc.y += zs[d] * wc[d].y;
                acc.z += zs[d] * wc[d].z; acc.w += zs[d] * wc[d].w;
            }
            kv4[lp][c] = acc;
        }
    }
    __syncthreads();

    // ---- attention: one thread per (line, head, row) ----
    {
        const int ln = t / TL;
        const int r  = t % TL;
        const int h  = r / L;           // wave-uniform for L=64
        const int i  = r % L;
        const int jb = ln * L;

        float4 z0 = zl4[0][jb + i], z1 = zl4[1][jb + i];
        const float zs[8] = {z0.x, z0.y, z0.z, z0.w, z1.x, z1.y, z1.z, z1.w};
        float4 q = make_float4(0.f, 0.f, 0.f, 0.f);
#pragma unroll
        for (int d = 0; d < 8; ++d) {
            float4 w = wq4[d][h];
            q.x += zs[d] * w.x; q.y += zs[d] * w.y;
            q.z += zs[d] * w.z; q.w += zs[d] * w.w;
        }
        q.x *= 0.5f; q.y *= 0.5f; q.z *= 0.5f; q.w *= 0.5f;   // E^-0.5

        const float L2E = 1.44269504f;
        float m = -3e38f, s = 0.f;
        float4 o = make_float4(0.f, 0.f, 0.f, 0.f);
#pragma unroll
        for (int j0 = 0; j0 < L; j0 += CH) {
            float dk[CH];
#pragma unroll
            for (int k = 0; k < CH; ++k) dk[k] = dot4(q, kv4[jb + j0 + k][h]);
            float cm = dk[0];
#pragma unroll
            for (int k = 1; k < CH; ++k) cm = fmaxf(cm, dk[k]);
            float mnew = fmaxf(m, cm);
            float c = exp2f((m - mnew) * L2E);
            m = mnew;
            const float nm = -m * L2E;
            s *= c;
            o.x *= c; o.y *= c; o.z *= c; o.w *= c;
#pragma unroll
            for (int k = 0; k < CH; ++k) {
                float p = exp2f(fmaf(dk[k], L2E, nm));
                s += p;
                float4 vv = kv4[jb + j0 + k][4 + h];
                o.x += p * vv.x; o.y += p * vv.y;
                o.z += p * vv.z; o.w += p * vv.w;
            }
        }
        const float inv = 1.f / s;
        olT4[h][jb + i] = make_float4(o.x * inv, o.y * inv, o.z * inv, o.w * inv);
    }
    __syncthreads();

    // ---- output projection, float4 per (position, d-quad) ----
    {
        const int dq = t & 1;
        float4 wr[16];
#pragma unroll
        for (int c = 0; c < 16; ++c) wr[c] = woq4[c][dq];
        float4 bo4 = bo4_s[dq];
        for (int idx = t; idx < LL * 2; idx += NT) {
            int ln, p;
            if (STG == 1) { int r = idx >> 1; ln = r % LINES; p = r / LINES; }
            else          { int r = idx >> 1; ln = r / L;     p = r % L;     }
            int lp = ln * L + p;
            float4 o0 = olT4[0][lp], o1 = olT4[1][lp];
            float4 o2 = olT4[2][lp], o3 = olT4[3][lp];
            const float oc[16] = {o0.x, o0.y, o0.z, o0.w, o1.x, o1.y, o1.z, o1.w,
                                  o2.x, o2.y, o2.z, o2.w, o3.x, o3.y, o3.z, o3.w};
            float4 acc = bo4;
#pragma unroll
            for (int c = 0; c < 16; ++c) {
                acc.x += oc[c] * wr[c].x; acc.y += oc[c] * wr[c].y;
                acc.z += oc[c] * wr[c].z; acc.w += oc[c] * wr[c].w;
            }
            float* gp = dst + line_base(ln) + (size_t)p * stride + dq * 4;
            if (ACCUM) {
                float4 old = *(const float4*)gp;
                acc.x += old.x; acc.y += old.y; acc.z += old.z; acc.w += old.w;
            }
            *(float4*)gp = acc;
        }
    }
}

// ---------------------------------------------------------------------------
__global__ __launch_bounds__(256)
void reduce_kernel(const float* __restrict__ z, const float* __restrict__ xt,
                   const float* __restrict__ Wc, float* __restrict__ accum) {
    const int b  = blockIdx.x >> 4;
    const int ij = ((blockIdx.x & 15) << 8) + threadIdx.x;
    float4 m0 = make_float4(-1e30f, -1e30f, -1e30f, -1e30f);
    float4 m1 = m0;
    for (int s = 0; s < SS; ++s) {
        size_t off = (((size_t)(b * SS + s)) * 4096 + ij) * 8;
        float4 a0 = *(const float4*)(z + off);
        float4 a1 = *(const float4*)(z + off + 4);
        float4 c0 = *(const float4*)(xt + off);
        float4 c1 = *(const float4*)(xt + off + 4);
        m0.x = fmaxf(m0.x, a0.x + c0.x); m0.y = fmaxf(m0.y, a0.y + c0.y);
        m0.z = fmaxf(m0.z, a0.z + c0.z); m0.w = fmaxf(m0.w, a0.w + c0.w);
        m1.x = fmaxf(m1.x, a1.x + c1.x); m1.y = fmaxf(m1.y, a1.y + c1.y);
        m1.z = fmaxf(m1.z, a1.z + c1.z); m1.w = fmaxf(m1.w, a1.w + c1.w);
    }
    float partial =
        m0.x * Wc[0 * 4096 + ij] + m0.y * Wc[1 * 4096 + ij] +
        m0.z * Wc[2 * 4096 + ij] + m0.w * Wc[3 * 4096 + ij] +
        m1.x * Wc[4 * 4096 + ij] + m1.y * Wc[5 * 4096 + ij] +
        m1.z * Wc[6 * 4096 + ij] + m1.w * Wc[7 * 4096 + ij];

    __shared__ float red[256];
    red[threadIdx.x] = partial;
    __syncthreads();
#pragma unroll
    for (int off = 128; off > 0; off >>= 1) {
        if (threadIdx.x < off) red[threadIdx.x] += red[threadIdx.x + off];
        __syncthreads();
    }
    if (threadIdx.x == 0) atomicAdd(&accum[b], red[0]);
}

__global__ void final_kernel(const float* __restrict__ accum,
                             const float* __restrict__ bc,
                             float* __restrict__ out) {
    int b = threadIdx.x;
    if (b < BB) out[b] = 1.f / (1.f + expf(-(accum[b] + bc[0])));
}

// ---------------------------------------------------------------------------
extern "C" void kernel_launch(void* const* d_in, const int* in_sizes, int n_in,
                              void* d_out, int out_size, void* d_ws, size_t ws_size,
                              hipStream_t stream) {
    const float* x      = (const float*)d_in[0];
    const float* conv_w = (const float*)d_in[1];
    const float* pos_s  = (const float*)d_in[2];
    const float* pos_h  = (const float*)d_in[3];
    const float* pos_w  = (const float*)d_in[4];
    const float* Wq     = (const float*)d_in[5];
    const float* Wkv    = (const float*)d_in[6];
    const float* Wo     = (const float*)d_in[7];
    const float* bo     = (const float*)d_in[8];
    const float* Wc     = (const float*)d_in[9];
    const float* bc     = (const float*)d_in[10];
    float* out = (float*)d_out;

    char* ws = (char*)d_ws;
    float* xt    = (float*)(ws);
    float* zA    = (float*)(ws + ZBYTES);
    float* zB    = (float*)(ws + 2 * ZBYTES);
    float* accum = (float*)(ws + 3 * ZBYTES);

    emb_kernel<<<NPOS / 256, 256, 0, stream>>>(x, conv_w, pos_s, pos_h, pos_w, xt);

    const float* cur = xt;
    float* bufs[2] = {zA, zB};
    int w = 0;
    for (int l = 0; l < NLAYER; ++l) {
        float* dstp = bufs[w];
        const float* wq0  = Wq  + (size_t)(l * 3 + 0) * 128;
        const float* wkv0 = Wkv + (size_t)(l * 3 + 0) * 256;
        const float* wo0  = Wo  + (size_t)(l * 3 + 0) * 128;
        const float* bo0  = bo  + (size_t)(l * 3 + 0) * 8;
        // a=0: attend over s (L=20), 4 lines/block, 320 thr, CH=20 (single chunk)
        attn_kernel<SS, SS, 4, false, 1><<<BB * IMM * IMM / 4, SS * HH * 4, 0, stream>>>(
            cur, dstp, wq0, wkv0, wo0, bo0, 8, 64, 512, 32768);
        // a=1: attend over i (L=64), 1 line/block, 256 thr, CH=8
        attn_kernel<IMM, 8, 1, true, 1><<<BB * SS * IMM, IMM * HH, 0, stream>>>(
            cur, dstp, wq0 + 128, wkv0 + 256, wo0 + 128, bo0 + 8, 8, 20, 32768, 512);
        // a=2: attend over j (L=64), contiguous lines -> position-fastest staging
        attn_kernel<IMM, 8, 1, true, 0><<<BB * SS * IMM, IMM * HH, 0, stream>>>(
            cur, dstp, wq0 + 256, wkv0 + 512, wo0 + 256, bo0 + 16, 512, 20, 32768, 8);
        cur = dstp;
        w ^= 1;
    }

    hipMemsetAsync(accum, 0, BB * sizeof(float), stream);
    reduce_kernel<<<BB * 16, 256, 0, stream>>>(cur, xt, Wc, accum);
    final_kernel<<<1, 64, 0, stream>>>(accum, bc, out);
}

// Round 8
// 460.195 us; speedup vs baseline: 1.5454x; 1.1530x over previous
//
#include <hip/hip_runtime.h>
#include <math.h>

#define DD 8
#define HH 4
#define EE 4
#define NLAYER 4
#define BB 4
#define SS 20
#define IMM 64

static constexpr int NPOS = BB * SS * IMM * IMM;          // 327680
static constexpr size_t ZBYTES = (size_t)NPOS * DD * 4;   // 10485760

// ---------------------------------------------------------------------------
__global__ __launch_bounds__(256)
void emb_kernel(const float* __restrict__ x, const float* __restrict__ conv_w,
                const float* __restrict__ pos_s, const float* __restrict__ pos_h,
                const float* __restrict__ pos_w, float* __restrict__ xt) {
    int idx = blockIdx.x * 256 + threadIdx.x;
    if (idx >= NPOS) return;
    int j = idx & 63;
    int i = (idx >> 6) & 63;
    int s = (idx >> 12) % SS;
    float xv = x[idx];
    float o[8];
#pragma unroll
    for (int d = 0; d < 8; ++d) {
        float v = xv * conv_w[d];
        v = v > 0.f ? v : 0.f;
        o[d] = v + pos_s[s * 8 + d] + pos_h[d * 64 + i] + pos_w[d * 64 + j];
    }
    float4* dst = (float4*)(xt + (size_t)idx * 8);
    dst[0] = make_float4(o[0], o[1], o[2], o[3]);
    dst[1] = make_float4(o[4], o[5], o[6], o[7]);
}

__device__ __forceinline__ float dot4(float4 a, float4 b) {
    return fmaf(a.w, b.w, fmaf(a.z, b.z, fmaf(a.y, b.y, a.x * b.x)));
}

// ---------------------------------------------------------------------------
// Axis attention, single-pass softmax with a-priori bound.
// Softmax is scale-invariant: o/s identical for p=exp(dot-B), any B>=max.
// B = |q'| * max_j |k_j| (Cauchy-Schwarz), with max|k|^2 per (line,head)
// computed during KV projection via LDS atomicMax (int-cast, valid for >=0).
// Inner loop: 4 QK fma + exp2 + sum + 4 PV fma per j; no max tracking.
template <int L, int LINES, bool ACCUM, int STG>
__global__ __launch_bounds__(HH * L * LINES, 8)
void attn_kernel(const float* __restrict__ src, float* __restrict__ dst,
                 const float* __restrict__ Wq, const float* __restrict__ Wkv,
                 const float* __restrict__ Wo, const float* __restrict__ bo,
                 int m0, int c1, int m1, int stride) {
    constexpr int TL = HH * L;           // threads per line
    constexpr int NT = TL * LINES;       // block size
    constexpr int LL = L * LINES;

    __shared__ float4 zl4[2][LL];        // z line, 2 quads per position
    __shared__ float4 kv4[LL][8];        // quads 0..3 = K heads, 4..7 = V heads
    __shared__ float4 olT4[HH][LL];      // attention out, head-major
    __shared__ float4 wq4[8][4];         // wq4[d][h]
    __shared__ float4 wkv4[8][8];        // wkv4[d][c]
    __shared__ float4 woq4[16][2];       // woq4[c][dq] = Wo[c][4dq..4dq+3]
    __shared__ float4 bo4_s[2];
    __shared__ float  Mh2[LINES][HH];    // max |k|^2 per (line, head)

    const int t = threadIdx.x;
    if (t < 32) wq4[t >> 2][t & 3]  = *(const float4*)(Wq  + t * 4);
    if (t < 64) wkv4[t >> 3][t & 7] = *(const float4*)(Wkv + t * 4);
    if (t < 32) woq4[t >> 1][t & 1] = *(const float4*)(Wo  + t * 4);
    if (t < 2)  bo4_s[t]            = *(const float4*)(bo  + t * 4);
    if (t < LINES * HH) Mh2[t / HH][t % HH] = 0.f;

    auto line_base = [&](int ln) -> size_t {
        int lid = blockIdx.x * LINES + ln;
        int u0 = lid & 63;
        int rest = lid >> 6;
        int u1 = rest % c1;
        int b  = rest / c1;
        return (size_t)b * 655360 + (size_t)u1 * m1 + (size_t)u0 * m0;
    };

    // ---- stage z ----
    for (int idx = t; idx < LL * 2; idx += NT) {
        int q, ln, p;
        if (STG == 1) { q = idx & 1; int r = idx >> 1; ln = r % LINES; p = r / LINES; }
        else          { q = idx & 1; int r = idx >> 1; ln = r / L;     p = r % L;     }
        zl4[q][ln * L + p] = *(const float4*)(src + line_base(ln) + (size_t)p * stride + q * 4);
    }
    __syncthreads();

    // ---- K,V projection (c fixed per thread); track max |k|^2 per head ----
    {
        const int c = t & 7;
        float4 wc[8];
#pragma unroll
        for (int d = 0; d < 8; ++d) wc[d] = wkv4[d][c];
        for (int idx = t; idx < LL * 8; idx += NT) {
            int lp = idx >> 3;
            float4 z0 = zl4[0][lp], z1 = zl4[1][lp];
            const float zs[8] = {z0.x, z0.y, z0.z, z0.w, z1.x, z1.y, z1.z, z1.w};
            float4 acc = make_float4(0.f, 0.f, 0.f, 0.f);
#pragma unroll
            for (int d = 0; d < 8; ++d) {
                acc.x += zs[d] * wc[d].x; acc.y += zs[d] * wc[d].y;
                acc.z += zs[d] * wc[d].z; acc.w += zs[d] * wc[d].w;
            }
            kv4[lp][c] = acc;
            if (c < 4)   // K quad: c == head index
                atomicMax((int*)&Mh2[lp / L][c], __float_as_int(dot4(acc, acc)));
        }
    }
    __syncthreads();

    // ---- attention: one thread per (line, head, row); single pass ----
    {
        const int ln = t / TL;
        const int r  = t % TL;
        const int h  = r / L;
        const int i  = r % L;
        const int jb = ln * L;

        float4 z0 = zl4[0][jb + i], z1 = zl4[1][jb + i];
        const float zs[8] = {z0.x, z0.y, z0.z, z0.w, z1.x, z1.y, z1.z, z1.w};
        float4 q = make_float4(0.f, 0.f, 0.f, 0.f);
#pragma unroll
        for (int d = 0; d < 8; ++d) {
            float4 w = wq4[d][h];
            q.x += zs[d] * w.x; q.y += zs[d] * w.y;
            q.z += zs[d] * w.z; q.w += zs[d] * w.w;
        }
        const float SC = 0.5f * 1.44269504f;   // E^-0.5 * log2(e)
        q.x *= SC; q.y *= SC; q.z *= SC; q.w *= SC;

        // bound (log2 units): B2 >= max_j q'.k_j by Cauchy-Schwarz
        const float B2 = sqrtf(dot4(q, q) * Mh2[ln][h]);

        float s = 0.f;
        float4 o = make_float4(0.f, 0.f, 0.f, 0.f);
#pragma unroll 8
        for (int j = 0; j < L; ++j) {
            float4 kk = kv4[jb + j][h];
            float p = __builtin_amdgcn_exp2f(dot4(q, kk) - B2);
            s += p;
            float4 vv = kv4[jb + j][4 + h];
            o.x += p * vv.x; o.y += p * vv.y;
            o.z += p * vv.z; o.w += p * vv.w;
        }
        const float inv = 1.f / fmaxf(s, 1e-37f);
        olT4[h][jb + i] = make_float4(o.x * inv, o.y * inv, o.z * inv, o.w * inv);
    }
    __syncthreads();

    // ---- output projection, float4 per (position, d-quad) ----
    {
        const int dq = t & 1;
        float4 wr[16];
#pragma unroll
        for (int c = 0; c < 16; ++c) wr[c] = woq4[c][dq];
        float4 bo4 = bo4_s[dq];
        for (int idx = t; idx < LL * 2; idx += NT) {
            int ln, p;
            if (STG == 1) { int r = idx >> 1; ln = r % LINES; p = r / LINES; }
            else          { int r = idx >> 1; ln = r / L;     p = r % L;     }
            int lp = ln * L + p;
            float4 o0 = olT4[0][lp], o1 = olT4[1][lp];
            float4 o2 = olT4[2][lp], o3 = olT4[3][lp];
            const float oc[16] = {o0.x, o0.y, o0.z, o0.w, o1.x, o1.y, o1.z, o1.w,
                                  o2.x, o2.y, o2.z, o2.w, o3.x, o3.y, o3.z, o3.w};
            float4 acc = bo4;
#pragma unroll
            for (int c = 0; c < 16; ++c) {
                acc.x += oc[c] * wr[c].x; acc.y += oc[c] * wr[c].y;
                acc.z += oc[c] * wr[c].z; acc.w += oc[c] * wr[c].w;
            }
            float* gp = dst + line_base(ln) + (size_t)p * stride + dq * 4;
            if (ACCUM) {
                float4 old = *(const float4*)gp;
                acc.x += old.x; acc.y += old.y; acc.z += old.z; acc.w += old.w;
            }
            *(float4*)gp = acc;
        }
    }
}

// ---------------------------------------------------------------------------
__global__ __launch_bounds__(256)
void reduce_kernel(const float* __restrict__ z, const float* __restrict__ xt,
                   const float* __restrict__ Wc, float* __restrict__ accum) {
    const int b  = blockIdx.x >> 4;
    const int ij = ((blockIdx.x & 15) << 8) + threadIdx.x;
    float4 m0 = make_float4(-1e30f, -1e30f, -1e30f, -1e30f);
    float4 m1 = m0;
    for (int s = 0; s < SS; ++s) {
        size_t off = (((size_t)(b * SS + s)) * 4096 + ij) * 8;
        float4 a0 = *(const float4*)(z + off);
        float4 a1 = *(const float4*)(z + off + 4);
        float4 c0 = *(const float4*)(xt + off);
        float4 c1 = *(const float4*)(xt + off + 4);
        m0.x = fmaxf(m0.x, a0.x + c0.x); m0.y = fmaxf(m0.y, a0.y + c0.y);
        m0.z = fmaxf(m0.z, a0.z + c0.z); m0.w = fmaxf(m0.w, a0.w + c0.w);
        m1.x = fmaxf(m1.x, a1.x + c1.x); m1.y = fmaxf(m1.y, a1.y + c1.y);
        m1.z = fmaxf(m1.z, a1.z + c1.z); m1.w = fmaxf(m1.w, a1.w + c1.w);
    }
    float partial =
        m0.x * Wc[0 * 4096 + ij] + m0.y * Wc[1 * 4096 + ij] +
        m0.z * Wc[2 * 4096 + ij] + m0.w * Wc[3 * 4096 + ij] +
        m1.x * Wc[4 * 4096 + ij] + m1.y * Wc[5 * 4096 + ij] +
        m1.z * Wc[6 * 4096 + ij] + m1.w * Wc[7 * 4096 + ij];

    __shared__ float red[256];
    red[threadIdx.x] = partial;
    __syncthreads();
#pragma unroll
    for (int off = 128; off > 0; off >>= 1) {
        if (threadIdx.x < off) red[threadIdx.x] += red[threadIdx.x + off];
        __syncthreads();
    }
    if (threadIdx.x == 0) atomicAdd(&accum[b], red[0]);
}

__global__ void final_kernel(const float* __restrict__ accum,
                             const float* __restrict__ bc,
                             float* __restrict__ out) {
    int b = threadIdx.x;
    if (b < BB) out[b] = 1.f / (1.f + expf(-(accum[b] + bc[0])));
}

// ---------------------------------------------------------------------------
extern "C" void kernel_launch(void* const* d_in, const int* in_sizes, int n_in,
                              void* d_out, int out_size, void* d_ws, size_t ws_size,
                              hipStream_t stream) {
    const float* x      = (const float*)d_in[0];
    const float* conv_w = (const float*)d_in[1];
    const float* pos_s  = (const float*)d_in[2];
    const float* pos_h  = (const float*)d_in[3];
    const float* pos_w  = (const float*)d_in[4];
    const float* Wq     = (const float*)d_in[5];
    const float* Wkv    = (const float*)d_in[6];
    const float* Wo     = (const float*)d_in[7];
    const float* bo     = (const float*)d_in[8];
    const float* Wc     = (const float*)d_in[9];
    const float* bc     = (const float*)d_in[10];
    float* out = (float*)d_out;

    char* ws = (char*)d_ws;
    float* xt    = (float*)(ws);
    float* zA    = (float*)(ws + ZBYTES);
    float* zB    = (float*)(ws + 2 * ZBYTES);
    float* accum = (float*)(ws + 3 * ZBYTES);

    emb_kernel<<<NPOS / 256, 256, 0, stream>>>(x, conv_w, pos_s, pos_h, pos_w, xt);

    const float* cur = xt;
    float* bufs[2] = {zA, zB};
    int w = 0;
    for (int l = 0; l < NLAYER; ++l) {
        float* dstp = bufs[w];
        const float* wq0  = Wq  + (size_t)(l * 3 + 0) * 128;
        const float* wkv0 = Wkv + (size_t)(l * 3 + 0) * 256;
        const float* wo0  = Wo  + (size_t)(l * 3 + 0) * 128;
        const float* bo0  = bo  + (size_t)(l * 3 + 0) * 8;
        // a=0: attend over s (L=20), 4 lines/block, 320 thr
        attn_kernel<SS, 4, false, 1><<<BB * IMM * IMM / 4, SS * HH * 4, 0, stream>>>(
            cur, dstp, wq0, wkv0, wo0, bo0, 8, 64, 512, 32768);
        // a=1: attend over i (L=64), 1 line/block, 256 thr
        attn_kernel<IMM, 1, true, 1><<<BB * SS * IMM, IMM * HH, 0, stream>>>(
            cur, dstp, wq0 + 128, wkv0 + 256, wo0 + 128, bo0 + 8, 8, 20, 32768, 512);
        // a=2: attend over j (L=64), contiguous lines -> position-fastest staging
        attn_kernel<IMM, 1, true, 0><<<BB * SS * IMM, IMM * HH, 0, stream>>>(
            cur, dstp, wq0 + 256, wkv0 + 512, wo0 + 256, bo0 + 16, 512, 20, 32768, 8);
        cur = dstp;
        w ^= 1;
    }

    hipMemsetAsync(accum, 0, BB * sizeof(float), stream);
    reduce_kernel<<<BB * 16, 256, 0, stream>>>(cur, xt, Wc, accum);
    final_kernel<<<1, 64, 0, stream>>>(accum, bc, out);
}

// Round 9
// 439.993 us; speedup vs baseline: 1.6163x; 1.0459x over previous
//
#include <hip/hip_runtime.h>
#include <math.h>

#define DD 8
#define HH 4
#define EE 4
#define NLAYER 4
#define BB 4
#define SS 20
#define IMM 64

static constexpr int NPOS = BB * SS * IMM * IMM;          // 327680
static constexpr size_t ZBYTES = (size_t)NPOS * DD * 4;   // 10485760

// ---------------------------------------------------------------------------
__global__ __launch_bounds__(256)
void emb_kernel(const float* __restrict__ x, const float* __restrict__ conv_w,
                const float* __restrict__ pos_s, const float* __restrict__ pos_h,
                const float* __restrict__ pos_w, float* __restrict__ xt) {
    int idx = blockIdx.x * 256 + threadIdx.x;
    if (idx >= NPOS) return;
    int j = idx & 63;
    int i = (idx >> 6) & 63;
    int s = (idx >> 12) % SS;
    float xv = x[idx];
    float o[8];
#pragma unroll
    for (int d = 0; d < 8; ++d) {
        float v = xv * conv_w[d];
        v = v > 0.f ? v : 0.f;
        o[d] = v + pos_s[s * 8 + d] + pos_h[d * 64 + i] + pos_w[d * 64 + j];
    }
    float4* dst = (float4*)(xt + (size_t)idx * 8);
    dst[0] = make_float4(o[0], o[1], o[2], o[3]);
    dst[1] = make_float4(o[4], o[5], o[6], o[7]);
}

__device__ __forceinline__ float dot4(float4 a, float4 b) {
    return fmaf(a.w, b.w, fmaf(a.z, b.z, fmaf(a.y, b.y, a.x * b.x)));
}
// dot with initial accumulator (folds the -B2 bias into the fma chain)
__device__ __forceinline__ float dot4i(float4 a, float4 b, float c0) {
    return fmaf(a.x, b.x, fmaf(a.y, b.y, fmaf(a.z, b.z, fmaf(a.w, b.w, c0))));
}

// ---------------------------------------------------------------------------
// Axis attention, single-pass softmax with a-priori Cauchy-Schwarz bound
// (p = exp2(q'.k - B2), B2 = |q'|*max|k| in log2 units; softmax is
// scale-invariant so any B2 >= max works). RPT query rows per thread:
// each K/V ds_read_b128 pair is amortized over RPT rows (LDS-issue relief).
// VGPR <= 64 enforced via __launch_bounds__(.,8) -> 32 waves/CU cap.
template <int L, int RPT, int LINES, bool ACCUM, int STG>
__global__ __launch_bounds__(HH * (L / RPT) * LINES, 8)
void attn_kernel(const float* __restrict__ src, float* __restrict__ dst,
                 const float* __restrict__ Wq, const float* __restrict__ Wkv,
                 const float* __restrict__ Wo, const float* __restrict__ bo,
                 int m0, int c1, int m1, int stride) {
    constexpr int RG = L / RPT;          // row-groups per (line, head)
    constexpr int TL = HH * RG;          // threads per line
    constexpr int NT = TL * LINES;       // block size
    constexpr int LL = L * LINES;

    __shared__ float4 zl4[2][LL];        // z line, 2 quads per position
    __shared__ float4 kv4[LL][8];        // quads 0..3 = K heads, 4..7 = V heads
    __shared__ float4 olT4[HH][LL];      // attention out, head-major
    __shared__ float4 wq4[8][4];         // wq4[d][h]
    __shared__ float4 wkv4[8][8];        // wkv4[d][c]
    __shared__ float4 woq4[16][2];       // woq4[c][dq] = Wo[c][4dq..4dq+3]
    __shared__ float4 bo4_s[2];
    __shared__ float  Mh2[LINES][HH];    // max |k|^2 per (line, head)

    const int t = threadIdx.x;
    if (t < 32) wq4[t >> 2][t & 3]  = *(const float4*)(Wq  + t * 4);
    if (t < 64) wkv4[t >> 3][t & 7] = *(const float4*)(Wkv + t * 4);
    if (t < 32) woq4[t >> 1][t & 1] = *(const float4*)(Wo  + t * 4);
    if (t < 2)  bo4_s[t]            = *(const float4*)(bo  + t * 4);
    if (t < LINES * HH) Mh2[t / HH][t % HH] = 0.f;

    auto line_base = [&](int ln) -> size_t {
        int lid = blockIdx.x * LINES + ln;
        int u0 = lid & 63;
        int rest = lid >> 6;
        int u1 = rest % c1;
        int b  = rest / c1;
        return (size_t)b * 655360 + (size_t)u1 * m1 + (size_t)u0 * m0;
    };

    // ---- stage z ----
    for (int idx = t; idx < LL * 2; idx += NT) {
        int q, ln, p;
        if (STG == 1) { q = idx & 1; int r = idx >> 1; ln = r % LINES; p = r / LINES; }
        else          { q = idx & 1; int r = idx >> 1; ln = r / L;     p = r % L;     }
        zl4[q][ln * L + p] = *(const float4*)(src + line_base(ln) + (size_t)p * stride + q * 4);
    }
    __syncthreads();

    // ---- K,V projection (c fixed per thread); track max |k|^2 per head ----
    {
        const int c = t & 7;
        float4 wc[8];
#pragma unroll
        for (int d = 0; d < 8; ++d) wc[d] = wkv4[d][c];
        for (int idx = t; idx < LL * 8; idx += NT) {
            int lp = idx >> 3;
            float4 z0 = zl4[0][lp], z1 = zl4[1][lp];
            const float zs[8] = {z0.x, z0.y, z0.z, z0.w, z1.x, z1.y, z1.z, z1.w};
            float4 acc = make_float4(0.f, 0.f, 0.f, 0.f);
#pragma unroll
            for (int d = 0; d < 8; ++d) {
                acc.x += zs[d] * wc[d].x; acc.y += zs[d] * wc[d].y;
                acc.z += zs[d] * wc[d].z; acc.w += zs[d] * wc[d].w;
            }
            kv4[lp][c] = acc;
            if (c < 4)   // K quad: c == head index
                atomicMax((int*)&Mh2[lp / L][c], __float_as_int(dot4(acc, acc)));
        }
    }
    __syncthreads();

    // ---- attention: thread = (line, head, RPT rows); single pass ----
    {
        const int ln = t / TL;
        const int r  = t % TL;
        const int h  = r / RG;
        const int rg = r % RG;
        const int jb = ln * L;
        const int i0 = rg * RPT;
        const float SC = 0.5f * 1.44269504f;   // E^-0.5 * log2(e)

        float4 q[RPT];
        float nB2[RPT];
        const float mh2 = Mh2[ln][h];
#pragma unroll
        for (int k = 0; k < RPT; ++k) {
            float4 z0 = zl4[0][jb + i0 + k], z1 = zl4[1][jb + i0 + k];
            const float zs[8] = {z0.x, z0.y, z0.z, z0.w, z1.x, z1.y, z1.z, z1.w};
            float4 acc = make_float4(0.f, 0.f, 0.f, 0.f);
#pragma unroll
            for (int d = 0; d < 8; ++d) {
                float4 w = wq4[d][h];
                acc.x += zs[d] * w.x; acc.y += zs[d] * w.y;
                acc.z += zs[d] * w.z; acc.w += zs[d] * w.w;
            }
            q[k] = make_float4(acc.x * SC, acc.y * SC, acc.z * SC, acc.w * SC);
            nB2[k] = -sqrtf(dot4(q[k], q[k]) * mh2);   // -(|q'| max|k|), log2 units
        }

        float s[RPT];
        float4 o[RPT];
#pragma unroll
        for (int k = 0; k < RPT; ++k) { s[k] = 0.f; o[k] = make_float4(0.f, 0.f, 0.f, 0.f); }
#pragma unroll 8
        for (int j = 0; j < L; ++j) {
            float4 kk = kv4[jb + j][h];
            float4 vv = kv4[jb + j][4 + h];
#pragma unroll
            for (int k = 0; k < RPT; ++k) {
                float p = __builtin_amdgcn_exp2f(dot4i(q[k], kk, nB2[k]));
                s[k] += p;
                o[k].x += p * vv.x; o[k].y += p * vv.y;
                o[k].z += p * vv.z; o[k].w += p * vv.w;
            }
        }
#pragma unroll
        for (int k = 0; k < RPT; ++k) {
            const float inv = 1.f / fmaxf(s[k], 1e-37f);
            olT4[h][jb + i0 + k] =
                make_float4(o[k].x * inv, o[k].y * inv, o[k].z * inv, o[k].w * inv);
        }
    }
    __syncthreads();

    // ---- output projection, float4 per (position, d-quad) ----
    {
        const int dq = t & 1;
        float4 wr[16];
#pragma unroll
        for (int c = 0; c < 16; ++c) wr[c] = woq4[c][dq];
        float4 bo4 = bo4_s[dq];
        for (int idx = t; idx < LL * 2; idx += NT) {
            int ln, p;
            if (STG == 1) { int r = idx >> 1; ln = r % LINES; p = r / LINES; }
            else          { int r = idx >> 1; ln = r / L;     p = r % L;     }
            int lp = ln * L + p;
            float4 o0 = olT4[0][lp], o1 = olT4[1][lp];
            float4 o2 = olT4[2][lp], o3 = olT4[3][lp];
            const float oc[16] = {o0.x, o0.y, o0.z, o0.w, o1.x, o1.y, o1.z, o1.w,
                                  o2.x, o2.y, o2.z, o2.w, o3.x, o3.y, o3.z, o3.w};
            float4 acc = bo4;
#pragma unroll
            for (int c = 0; c < 16; ++c) {
                acc.x += oc[c] * wr[c].x; acc.y += oc[c] * wr[c].y;
                acc.z += oc[c] * wr[c].z; acc.w += oc[c] * wr[c].w;
            }
            float* gp = dst + line_base(ln) + (size_t)p * stride + dq * 4;
            if (ACCUM) {
                float4 old = *(const float4*)gp;
                acc.x += old.x; acc.y += old.y; acc.z += old.z; acc.w += old.w;
            }
            *(float4*)gp = acc;
        }
    }
}

// ---------------------------------------------------------------------------
__global__ __launch_bounds__(256)
void reduce_kernel(const float* __restrict__ z, const float* __restrict__ xt,
                   const float* __restrict__ Wc, float* __restrict__ accum) {
    const int b  = blockIdx.x >> 4;
    const int ij = ((blockIdx.x & 15) << 8) + threadIdx.x;
    float4 m0 = make_float4(-1e30f, -1e30f, -1e30f, -1e30f);
    float4 m1 = m0;
    for (int s = 0; s < SS; ++s) {
        size_t off = (((size_t)(b * SS + s)) * 4096 + ij) * 8;
        float4 a0 = *(const float4*)(z + off);
        float4 a1 = *(const float4*)(z + off + 4);
        float4 c0 = *(const float4*)(xt + off);
        float4 c1 = *(const float4*)(xt + off + 4);
        m0.x = fmaxf(m0.x, a0.x + c0.x); m0.y = fmaxf(m0.y, a0.y + c0.y);
        m0.z = fmaxf(m0.z, a0.z + c0.z); m0.w = fmaxf(m0.w, a0.w + c0.w);
        m1.x = fmaxf(m1.x, a1.x + c1.x); m1.y = fmaxf(m1.y, a1.y + c1.y);
        m1.z = fmaxf(m1.z, a1.z + c1.z); m1.w = fmaxf(m1.w, a1.w + c1.w);
    }
    float partial =
        m0.x * Wc[0 * 4096 + ij] + m0.y * Wc[1 * 4096 + ij] +
        m0.z * Wc[2 * 4096 + ij] + m0.w * Wc[3 * 4096 + ij] +
        m1.x * Wc[4 * 4096 + ij] + m1.y * Wc[5 * 4096 + ij] +
        m1.z * Wc[6 * 4096 + ij] + m1.w * Wc[7 * 4096 + ij];

    __shared__ float red[256];
    red[threadIdx.x] = partial;
    __syncthreads();
#pragma unroll
    for (int off = 128; off > 0; off >>= 1) {
        if (threadIdx.x < off) red[threadIdx.x] += red[threadIdx.x + off];
        __syncthreads();
    }
    if (threadIdx.x == 0) atomicAdd(&accum[b], red[0]);
}

__global__ void final_kernel(const float* __restrict__ accum,
                             const float* __restrict__ bc,
                             float* __restrict__ out) {
    int b = threadIdx.x;
    if (b < BB) out[b] = 1.f / (1.f + expf(-(accum[b] + bc[0])));
}

// ---------------------------------------------------------------------------
extern "C" void kernel_launch(void* const* d_in, const int* in_sizes, int n_in,
                              void* d_out, int out_size, void* d_ws, size_t ws_size,
                              hipStream_t stream) {
    const float* x      = (const float*)d_in[0];
    const float* conv_w = (const float*)d_in[1];
    const float* pos_s  = (const float*)d_in[2];
    const float* pos_h  = (const float*)d_in[3];
    const float* pos_w  = (const float*)d_in[4];
    const float* Wq     = (const float*)d_in[5];
    const float* Wkv    = (const float*)d_in[6];
    const float* Wo     = (const float*)d_in[7];
    const float* bo     = (const float*)d_in[8];
    const float* Wc     = (const float*)d_in[9];
    const float* bc     = (const float*)d_in[10];
    float* out = (float*)d_out;

    char* ws = (char*)d_ws;
    float* xt    = (float*)(ws);
    float* zA    = (float*)(ws + ZBYTES);
    float* zB    = (float*)(ws + 2 * ZBYTES);
    float* accum = (float*)(ws + 3 * ZBYTES);

    emb_kernel<<<NPOS / 256, 256, 0, stream>>>(x, conv_w, pos_s, pos_h, pos_w, xt);

    const float* cur = xt;
    float* bufs[2] = {zA, zB};
    int w = 0;
    for (int l = 0; l < NLAYER; ++l) {
        float* dstp = bufs[w];
        const float* wq0  = Wq  + (size_t)(l * 3 + 0) * 128;
        const float* wkv0 = Wkv + (size_t)(l * 3 + 0) * 256;
        const float* wo0  = Wo  + (size_t)(l * 3 + 0) * 128;
        const float* bo0  = bo  + (size_t)(l * 3 + 0) * 8;
        // a=0: attend over s (L=20), RPT=2, 8 lines/block, 320 thr
        attn_kernel<SS, 2, 8, false, 1><<<BB * IMM * IMM / 8, HH * (SS / 2) * 8, 0, stream>>>(
            cur, dstp, wq0, wkv0, wo0, bo0, 8, 64, 512, 32768);
        // a=1: attend over i (L=64), RPT=2, 2 lines/block, 256 thr
        attn_kernel<IMM, 2, 2, true, 1><<<BB * SS * IMM / 2, HH * (IMM / 2) * 2, 0, stream>>>(
            cur, dstp, wq0 + 128, wkv0 + 256, wo0 + 128, bo0 + 8, 8, 20, 32768, 512);
        // a=2: attend over j (L=64), RPT=2, position-fastest staging
        attn_kernel<IMM, 2, 2, true, 0><<<BB * SS * IMM / 2, HH * (IMM / 2) * 2, 0, stream>>>(
            cur, dstp, wq0 + 256, wkv0 + 512, wo0 + 256, bo0 + 16, 512, 20, 32768, 8);
        cur = dstp;
        w ^= 1;
    }

    hipMemsetAsync(accum, 0, BB * sizeof(float), stream);
    reduce_kernel<<<BB * 16, 256, 0, stream>>>(cur, xt, Wc, accum);
    final_kernel<<<1, 64, 0, stream>>>(accum, bc, out);
}